// Round 10
// baseline (216.995 us; speedup 1.0000x reference)
//
#include <hip/hip_runtime.h>
#include <cstddef>

#define NB 32
#define NF 64
#define NL 8192
#define NP 96
#define NH 8
#define TSPLIT 16

// ws layout in floats:
#define WS_MEAN 0           // 2048
#define WS_STD  2048        // 2048
#define WS_RSTD 4096        // 2048
#define WS_KV   6144        // NB*NH*64 = 16384
#define WS_Z    22528       // NB*NH*8  = 2048
#define WS_OUT2 24576       // NB*NP*NF = 196608 -> ends 221184
#define WS_MUN  221184      // NB*NL = 262144
#define WS_RSN  483328      // NB*NL = 262144
#define WS_WLB  745472      // NP*NL bf16 = 393216 floats
#define WS_XNB  1138688     // (unused since R10: xnb round-trip eliminated)
#define WS_YT   9527296     // NB*NF*NL bf16 = 8388608 floats -> ends 17915904
#define WS_WKV  17915904    // prefolded WkB|WvB images: 2*64*72 bf16 = 4608 floats
#define WS_WQO  17920512    // prefolded WqB|WoB images: 4608 floats
#define WS_SKT  17925120    // 256 floats: Sk|Tk+bk|Sv|Tv+bv
#define WS_SQT  17925376    // 128 floats: Sq|Tq+bq   (total ~71.7 MB)

typedef __bf16 bfx8 __attribute__((ext_vector_type(8)));
typedef float f32x4 __attribute__((ext_vector_type(4)));
#define MFMA16(a, b, c) __builtin_amdgcn_mfma_f32_16x16x32_bf16((a), (b), (c), 0, 0, 0)

// ---- bf16 helpers (manual RNE — the ONLY proven spill-free + correct path:
// R3/R4: (__bf16) cast spills to scratch (+20MB WRITE_SIZE); R5: inline-asm
// v_cvt_pk_bf16_f32 produced NaN. Do not change without disasm verification. ----
__device__ __forceinline__ unsigned short f2bf(float f) {
  unsigned u = __float_as_uint(f);
  unsigned r = u + 0x7FFFu + ((u >> 16) & 1u);
  return (unsigned short)(r >> 16);
}
__device__ __forceinline__ unsigned packbf2(float lo, float hi) {
  return (unsigned)f2bf(lo) | ((unsigned)f2bf(hi) << 16);
}
__device__ __forceinline__ float bflo(unsigned d) { return __uint_as_float(d << 16); }
__device__ __forceinline__ float bfhi(unsigned d) { return __uint_as_float(d & 0xFFFF0000u); }
__device__ __forceinline__ float bf1(unsigned short s) { return __uint_as_float(((unsigned)s) << 16); }

__device__ __forceinline__ bfx8 ldfrag(const unsigned short* p) {
  uint4 u = *(const uint4*)p;
  return __builtin_bit_cast(bfx8, u);
}

// ---------------- K_pre: RevIN stats + Wlin tiling + zero accum + weight prefold ----------------
// grid = NB*NF (stats+zero) + 384 (wlb) + 2 (weight fold K/V and Q/O).
__global__ __launch_bounds__(256) void k_pre(
    const float* __restrict__ x, const float* __restrict__ Wlin,
    const float* __restrict__ lnw, const float* __restrict__ lnb,
    const float* __restrict__ Wk, const float* __restrict__ bk,
    const float* __restrict__ Wv, const float* __restrict__ bv,
    const float* __restrict__ Wq, const float* __restrict__ bq,
    const float* __restrict__ Wo,
    float* __restrict__ wmean, float* __restrict__ wstd, float* __restrict__ wrstd,
    unsigned short* __restrict__ wlb, float* __restrict__ zz,
    unsigned short* __restrict__ wWkv, unsigned short* __restrict__ wWqo,
    float* __restrict__ wSkT, float* __restrict__ wSqT) {
  __shared__ float r1[4], r2[4];
  const int bid = blockIdx.x, tid = threadIdx.x;
  if (bid < NB * NF) {
    const float4* row4 = (const float4*)(x + (size_t)bid * NL);
    float s1 = 0.f, s2 = 0.f;
#pragma unroll
    for (int i = 0; i < NL / 4 / 256; i++) {
      float4 v = row4[tid + i * 256];
      s1 += v.x + v.y + v.z + v.w;
      s2 += v.x * v.x + v.y * v.y + v.z * v.z + v.w * v.w;
    }
#pragma unroll
    for (int off = 32; off > 0; off >>= 1) {
      s1 += __shfl_down(s1, off, 64);
      s2 += __shfl_down(s2, off, 64);
    }
    if ((tid & 63) == 0) { r1[tid >> 6] = s1; r2[tid >> 6] = s2; }
    __syncthreads();
    if (tid == 0) {
      s1 = r1[0] + r1[1] + r1[2] + r1[3];
      s2 = r2[0] + r2[1] + r2[2] + r2[3];
      float m = s1 * (1.f / NL);
      float var = (s2 - (float)NL * m * m) * (1.f / (NL - 1));
      float sd = sqrtf(fmaxf(var, 0.f)) + 1e-5f;
      wmean[bid] = m;
      wstd[bid] = sd;
      wrstd[bid] = 1.f / sd;
    }
    // zero the atomic accumulators (wKV 16384 + wZ 2048 + out2 196608 = 215040 floats)
    unsigned zi = (unsigned)bid * 256u + (unsigned)tid;
    if (zi < 215040u) zz[zi] = 0.f;
  } else if (bid < NB * NF + NP * NL / 8 / 256) {
    int i = (bid - NB * NF) * 256 + tid;  // NP*NL/8 threads
    int p = i >> 10;                      // NL/8 = 1024
    int l8 = (i & 1023) * 8;
    float4 va = *(const float4*)&Wlin[(size_t)p * NL + l8];
    float4 vb = *(const float4*)&Wlin[(size_t)p * NL + l8 + 4];
    uint4 o;
    o.x = packbf2(va.x, va.y); o.y = packbf2(va.z, va.w);
    o.z = packbf2(vb.x, vb.y); o.w = packbf2(vb.z, vb.w);
    *(uint4*)&wlb[(((size_t)(l8 >> 5)) * NP + p) * 32 + (l8 & 31)] = o;
  } else if (bid == NB * NF + NP * NL / 8 / 256) {
    // ---- fold K/V weights (lnw) + S/T(+bias) into global images ----
    int jj = tid >> 2, g = tid & 3;
    int f0 = g * 16;
    float tkp = 0.f, tvp = 0.f, skp = 0.f, svp = 0.f;
#pragma unroll
    for (int i = 0; i < 4; i++) {
      int f = f0 + i * 4;
      float4 wk4 = *(const float4*)&Wk[jj * NF + f];
      float4 wv4 = *(const float4*)&Wv[jj * NF + f];
      float4 lw  = *(const float4*)&lnw[f];
      float4 lb  = *(const float4*)&lnb[f];
      uint2 pk2, pv2;
      pk2.x = packbf2(wk4.x * lw.x, wk4.y * lw.y);
      pk2.y = packbf2(wk4.z * lw.z, wk4.w * lw.w);
      pv2.x = packbf2(wv4.x * lw.x, wv4.y * lw.y);
      pv2.y = packbf2(wv4.z * lw.z, wv4.w * lw.w);
      *(uint2*)&wWkv[jj * 72 + f] = pk2;
      *(uint2*)&wWkv[4608 + jj * 72 + f] = pv2;
      tkp += lb.x * wk4.x + lb.y * wk4.y + lb.z * wk4.z + lb.w * wk4.w;
      tvp += lb.x * wv4.x + lb.y * wv4.y + lb.z * wv4.z + lb.w * wv4.w;
      skp += bflo(pk2.x) + bfhi(pk2.x) + bflo(pk2.y) + bfhi(pk2.y);
      svp += bflo(pv2.x) + bfhi(pv2.x) + bflo(pv2.y) + bfhi(pv2.y);
    }
    tkp += __shfl_xor(tkp, 1, 64); tkp += __shfl_xor(tkp, 2, 64);
    tvp += __shfl_xor(tvp, 1, 64); tvp += __shfl_xor(tvp, 2, 64);
    skp += __shfl_xor(skp, 1, 64); skp += __shfl_xor(skp, 2, 64);
    svp += __shfl_xor(svp, 1, 64); svp += __shfl_xor(svp, 2, 64);
    if (g == 0) {
      wSkT[jj]       = skp;
      wSkT[64 + jj]  = tkp + bk[jj];
      wSkT[128 + jj] = svp;
      wSkT[192 + jj] = tvp + bv[jj];
    }
  } else {
    // ---- fold Q (lnw) + raw Wo + Sq/Tq(+bq) ----
    int jj = tid >> 2, g = tid & 3;
    int f0 = g * 16;
    float tqp = 0.f, sqp = 0.f;
#pragma unroll
    for (int i = 0; i < 4; i++) {
      int f = f0 + i * 4;
      float4 wq4 = *(const float4*)&Wq[jj * NF + f];
      float4 wo4 = *(const float4*)&Wo[jj * NF + f];
      float4 lw  = *(const float4*)&lnw[f];
      float4 lb  = *(const float4*)&lnb[f];
      uint2 pq2, po2;
      pq2.x = packbf2(wq4.x * lw.x, wq4.y * lw.y);
      pq2.y = packbf2(wq4.z * lw.z, wq4.w * lw.w);
      po2.x = packbf2(wo4.x, wo4.y);
      po2.y = packbf2(wo4.z, wo4.w);
      *(uint2*)&wWqo[jj * 72 + f] = pq2;
      *(uint2*)&wWqo[4608 + jj * 72 + f] = po2;
      tqp += lb.x * wq4.x + lb.y * wq4.y + lb.z * wq4.z + lb.w * wq4.w;
      sqp += bflo(pq2.x) + bfhi(pq2.x) + bflo(pq2.y) + bfhi(pq2.y);
    }
    tqp += __shfl_xor(tqp, 1, 64); tqp += __shfl_xor(tqp, 2, 64);
    sqp += __shfl_xor(sqp, 1, 64); sqp += __shfl_xor(sqp, 2, 64);
    if (g == 0) { wSqT[jj] = sqp; wSqT[64 + jj] = tqp + bq[jj]; }
  }
}

// ---------------- K2: K/V projection (MFMA) + KV,Z accumulation ----------------
// 256 threads, 128 l per block, grid NB*64.  LDS 20992 B.
// R10: xnb export removed (k_qy recomputes xn from x, which is L3-resident).
__global__ __launch_bounds__(256, 4) void k_kv(
    const float* __restrict__ x,
    const float* __restrict__ gamma, const float* __restrict__ beta,
    const unsigned short* __restrict__ wWkv, const float* __restrict__ wSkT,
    const float* __restrict__ wmean, const float* __restrict__ wrstd,
    float* __restrict__ wKV, float* __restrict__ wZ,
    float* __restrict__ wmun, float* __restrict__ wrsn) {
  __shared__ __align__(16) char smem[20992];
  unsigned short* hA  = (unsigned short*)smem;            // [128][72] xn bf16
  unsigned short* pKh = (unsigned short*)smem;            // overlay: [64 j][72] l-half
  unsigned short* pVh = (unsigned short*)(smem + 9216);   // overlay: [64 j][72] l-half
  float* SkT = (float*)(smem + 18432);  // [256] Sk|Tk|Sv|Tv
  float* mun = (float*)(smem + 19456);  // [128]
  float* rsn = (float*)(smem + 19968);  // [128]
  float* cbc = (float*)(smem + 20480);  // [128]  (cb,cc) pairs per f

  const int tid = threadIdx.x;
  const int b = blockIdx.x >> 6;
  const int tI = blockIdx.x & 63;
  const int L0 = tI * 128;
  const int lane = tid & 63, wv = tid >> 6;
  const int mm = lane & 15, qd = lane >> 4;

  // ---- phase 0: RevIN fold constants + SkT copy ----
  if (tid < 64) {
    float cb = wrstd[b * NF + tid] * gamma[tid];
    cbc[2 * tid] = cb;
    cbc[2 * tid + 1] = beta[tid] - wmean[b * NF + tid] * cb;
  }
  SkT[tid] = wSkT[tid];
  __syncthreads();

  // ---- phase 1: thread = (l-quad lt, f-octet fg); 8x dwordx4 loads ----
  {
    const int lt = tid >> 3;       // 0..31
    const int fg = tid & 7;        // 0..7
    const int l0q = lt * 4;
    const float* xp = x + ((size_t)(b * NF + fg * 8)) * NL + L0 + l0q;
    f32x4 v[8];
#pragma unroll
    for (int i = 0; i < 8; i++) v[i] = *(const f32x4*)(xp + (size_t)i * NL);
    float a[8][4];
#pragma unroll
    for (int i = 0; i < 4; i++) {
      float4 c = *(const float4*)&cbc[fg * 16 + i * 4];  // cb,cc for f=fg*8+2i, +2i+1
#pragma unroll
      for (int j = 0; j < 4; j++) {
        a[2 * i][j]     = fmaf(v[2 * i][j], c.x, c.y);
        a[2 * i + 1][j] = fmaf(v[2 * i + 1][j], c.z, c.w);
      }
    }
    float s1[4], s2[4];
#pragma unroll
    for (int j = 0; j < 4; j++) {
      s1[j] = 0.f; s2[j] = 0.f;
#pragma unroll
      for (int i = 0; i < 8; i++) {
        s1[j] += a[i][j];
        s2[j] = fmaf(a[i][j], a[i][j], s2[j]);
      }
    }
    // reduce over fg (lane bits 0..2)
#pragma unroll
    for (int m = 1; m <= 4; m <<= 1) {
#pragma unroll
      for (int j = 0; j < 4; j++) {
        s1[j] += __shfl_xor(s1[j], m, 64);
        s2[j] += __shfl_xor(s2[j], m, 64);
      }
    }
    // pack + store to LDS straight from regs (no global export — R10)
#pragma unroll
    for (int j = 0; j < 4; j++) {
      uint4 o;
      o.x = packbf2(a[0][j], a[1][j]);
      o.y = packbf2(a[2][j], a[3][j]);
      o.z = packbf2(a[4][j], a[5][j]);
      o.w = packbf2(a[6][j], a[7][j]);
      *(uint4*)&hA[(l0q + j) * 72 + fg * 8] = o;
    }
    if (fg == 0) {
      float mv[4], rv[4];
#pragma unroll
      for (int j = 0; j < 4; j++) {
        float mu = s1[j] * (1.f / NF);
        float var = s2[j] * (1.f / NF) - mu * mu;
        mv[j] = mu;
        rv[j] = rsqrtf(fmaxf(var, 0.f) + 1e-5f);
      }
      float4 m4 = {mv[0], mv[1], mv[2], mv[3]};
      float4 r4 = {rv[0], rv[1], rv[2], rv[3]};
      *(float4*)&mun[l0q] = m4;
      *(float4*)&rsn[l0q] = r4;
      *(float4*)&wmun[(size_t)b * NL + L0 + l0q] = m4;
      *(float4*)&wrsn[(size_t)b * NL + L0 + l0q] = r4;
    }
  }
  __syncthreads();

  // ---- projection MFMA: A-frags from LDS hA, B-frags from global wWkv (L2-hot) ----
  const f32x4 fz = {0.f, 0.f, 0.f, 0.f};
  f32x4 kacc[2][4], vacc[2][4];
#pragma unroll
  for (int i = 0; i < 2; i++)
#pragma unroll
    for (int jt = 0; jt < 4; jt++) { kacc[i][jt] = fz; vacc[i][jt] = fz; }

#pragma unroll
  for (int kc = 0; kc < 2; kc++) {
    bfx8 a0 = ldfrag(&hA[(wv * 32 + mm) * 72 + kc * 32 + qd * 8]);
    bfx8 a1 = ldfrag(&hA[(wv * 32 + 16 + mm) * 72 + kc * 32 + qd * 8]);
#pragma unroll
    for (int jt = 0; jt < 4; jt++) {
      bfx8 bkf = ldfrag(&wWkv[(jt * 16 + mm) * 72 + kc * 32 + qd * 8]);
      bfx8 bvf = ldfrag(&wWkv[4608 + (jt * 16 + mm) * 72 + kc * 32 + qd * 8]);
      kacc[0][jt] = MFMA16(a0, bkf, kacc[0][jt]);
      kacc[1][jt] = MFMA16(a1, bkf, kacc[1][jt]);
      vacc[0][jt] = MFMA16(a0, bvf, vacc[0][jt]);
      vacc[1][jt] = MFMA16(a1, bvf, vacc[1][jt]);
    }
  }

  // ---- postfix: K = rs*(raw - mu*Sk) + Tk -> phi;  V likewise (no phi) ----
#pragma unroll
  for (int lt2 = 0; lt2 < 2; lt2++) {
    float4 mu4 = *(const float4*)&mun[wv * 32 + lt2 * 16 + qd * 4];
    float4 rs4 = *(const float4*)&rsn[wv * 32 + lt2 * 16 + qd * 4];
    float muv[4] = {mu4.x, mu4.y, mu4.z, mu4.w};
    float rsv[4] = {rs4.x, rs4.y, rs4.z, rs4.w};
#pragma unroll
    for (int jt = 0; jt < 4; jt++) {
      int j = jt * 16 + mm;
      float Sk = SkT[j], Tk = SkT[64 + j], Sv = SkT[128 + j], Tv = SkT[192 + j];
#pragma unroll
      for (int r = 0; r < 4; r++) {
        float kk = rsv[r] * (kacc[lt2][jt][r] - muv[r] * Sk) + Tk;
        kacc[lt2][jt][r] = (kk > 0.f) ? (kk + 1.f) : __expf(kk);
        vacc[lt2][jt][r] = rsv[r] * (vacc[lt2][jt][r] - muv[r] * Sv) + Tv;
      }
    }
  }

  // ---- Z from f32 kacc regs: wave wv covers l = wv*32..+32 ----
  {
#pragma unroll
    for (int jt = 0; jt < 4; jt++) {
      float z = 0.f;
#pragma unroll
      for (int lt2 = 0; lt2 < 2; lt2++)
#pragma unroll
        for (int r = 0; r < 4; r++) z += kacc[lt2][jt][r];
      z += __shfl_xor(z, 16, 64);
      z += __shfl_xor(z, 32, 64);
      if (qd == 0) atomicAdd(&wZ[b * 64 + jt * 16 + mm], z);
    }
  }

  // ---- KV reduction in two l-halves through the 18.4 KB overlay (hA dead) ----
  {
    f32x4 racc = fz;
#pragma unroll
    for (int h = 0; h < 2; h++) {
      __syncthreads();   // prior reads of overlay (or hA) complete
      if ((wv >> 1) == h) {
#pragma unroll
        for (int lt2 = 0; lt2 < 2; lt2++) {
          int lcol = (wv & 1) * 32 + lt2 * 16 + qd * 4;
#pragma unroll
          for (int jt = 0; jt < 4; jt++) {
            int j = jt * 16 + mm;
            uint2 dk, dv;
            dk.x = packbf2(kacc[lt2][jt][0], kacc[lt2][jt][1]);
            dk.y = packbf2(kacc[lt2][jt][2], kacc[lt2][jt][3]);
            dv.x = packbf2(vacc[lt2][jt][0], vacc[lt2][jt][1]);
            dv.y = packbf2(vacc[lt2][jt][2], vacc[lt2][jt][3]);
            *(uint2*)&pKh[j * 72 + lcol] = dk;
            *(uint2*)&pVh[j * 72 + lcol] = dv;
          }
        }
      }
      __syncthreads();
#pragma unroll
      for (int kb = 0; kb < 2; kb++) {
        bfx8 ak  = ldfrag(&pKh[(wv * 16 + mm) * 72 + kb * 32 + qd * 8]);
        bfx8 bv8 = ldfrag(&pVh[(wv * 16 + mm) * 72 + kb * 32 + qd * 8]);
        racc = MFMA16(ak, bv8, racc);
      }
    }
    int eh = mm >> 3, e = mm & 7;
#pragma unroll
    for (int r = 0; r < 4; r++) {
      int row = qd * 4 + r;
      if ((row >> 3) == eh)
        atomicAdd(&wKV[(b * NH + wv * 2 + eh) * 64 + (row & 7) * 8 + e], racc[r]);
    }
  }
}

// ---------------- K3: Q MFMA + readout + O MFMA + residual -> yT tiled bf16 ----------------
// 256 threads, 128 l, grid NB*64.  LDS 40960 B -> 4 blocks/CU.
// R10: xn recomputed from x (bit-identical affine+pack); residual kept in xnRes LDS.
__global__ __launch_bounds__(256, 4) void k_qy(
    const float* __restrict__ x,
    const float* __restrict__ gamma, const float* __restrict__ beta,
    const unsigned short* __restrict__ wWqo, const float* __restrict__ wSqT,
    const float* __restrict__ bo,
    const float* __restrict__ wmean, const float* __restrict__ wrstd,
    const float* __restrict__ wmun, const float* __restrict__ wrsn,
    const float* __restrict__ wKV, const float* __restrict__ wZ,
    unsigned short* __restrict__ ytb) {
  __shared__ __align__(16) char smem[40960];
  unsigned short* hA  = (unsigned short*)smem;             // [128][72] xn bf16 -> overlaid by att
  unsigned short* qaA = (unsigned short*)smem;             // [128 l][72] phi(Q)/att
  unsigned short* xnR = (unsigned short*)(smem + 18432);   // [128][72] xn residual copy
  float* kvz  = (float*)(smem + 36864);  // [640] KV|Z|bo
  float* mun  = (float*)(smem + 39424);  // [128]
  float* rsn  = (float*)(smem + 39936);  // [128]
  float* SqTq = (float*)(smem + 40448);  // [128]

  const int tid = threadIdx.x;
  const int b = blockIdx.x >> 6;
  const int tI = blockIdx.x & 63;
  const int L0 = tI * 128;
  const int lane = tid & 63, wv = tid >> 6;
  const int mm = lane & 15, qd = lane >> 4;

  // ---- phase 0: kvz/bo + SqT + mu/rs + xn recompute (x is L3-hot) ----
  for (int i = tid; i < 640; i += 256)
    kvz[i] = (i < 512) ? wKV[b * 512 + i] : (i < 576 ? wZ[b * 64 + i - 512] : bo[i - 576]);
  if (tid < 128) SqTq[tid] = wSqT[tid];
  if (tid < 64) {
    int h = tid >> 5, i = tid & 31;
    const float* src = h ? wrsn : wmun;
    float4 v = *(const float4*)&src[(size_t)b * NL + L0 + i * 4];
    *(float4*)&((h ? rsn : mun)[i * 4]) = v;
  }
  {
    const int lt = tid >> 3, fg = tid & 7;
    const int l0q = lt * 4;
    float cb[8], cc[8];
    {
      float4 g0 = *(const float4*)&gamma[fg * 8], g1 = *(const float4*)&gamma[fg * 8 + 4];
      float4 be0 = *(const float4*)&beta[fg * 8], be1 = *(const float4*)&beta[fg * 8 + 4];
      float4 m0 = *(const float4*)&wmean[b * NF + fg * 8], m1 = *(const float4*)&wmean[b * NF + fg * 8 + 4];
      float4 r0 = *(const float4*)&wrstd[b * NF + fg * 8], r1 = *(const float4*)&wrstd[b * NF + fg * 8 + 4];
      cb[0] = r0.x * g0.x; cb[1] = r0.y * g0.y; cb[2] = r0.z * g0.z; cb[3] = r0.w * g0.w;
      cb[4] = r1.x * g1.x; cb[5] = r1.y * g1.y; cb[6] = r1.z * g1.z; cb[7] = r1.w * g1.w;
      cc[0] = be0.x - m0.x * cb[0]; cc[1] = be0.y - m0.y * cb[1];
      cc[2] = be0.z - m0.z * cb[2]; cc[3] = be0.w - m0.w * cb[3];
      cc[4] = be1.x - m1.x * cb[4]; cc[5] = be1.y - m1.y * cb[5];
      cc[6] = be1.z - m1.z * cb[6]; cc[7] = be1.w - m1.w * cb[7];
    }
    const float* xp = x + ((size_t)(b * NF + fg * 8)) * NL + L0 + l0q;
    f32x4 v[8];
#pragma unroll
    for (int i = 0; i < 8; i++) v[i] = *(const f32x4*)(xp + (size_t)i * NL);
#pragma unroll
    for (int j = 0; j < 4; j++) {
      uint4 o;
      o.x = packbf2(fmaf(v[0][j], cb[0], cc[0]), fmaf(v[1][j], cb[1], cc[1]));
      o.y = packbf2(fmaf(v[2][j], cb[2], cc[2]), fmaf(v[3][j], cb[3], cc[3]));
      o.z = packbf2(fmaf(v[4][j], cb[4], cc[4]), fmaf(v[5][j], cb[5], cc[5]));
      o.w = packbf2(fmaf(v[6][j], cb[6], cc[6]), fmaf(v[7][j], cb[7], cc[7]));
      *(uint4*)&hA[(l0q + j) * 72 + fg * 8] = o;
      *(uint4*)&xnR[(l0q + j) * 72 + fg * 8] = o;
    }
  }
  __syncthreads();

  const f32x4 fz = {0.f, 0.f, 0.f, 0.f};

  // ---- Q-MFMA (B-frags from global); postfix+phi scatters into qaA ----
  {
    f32x4 qacc[2][4];
#pragma unroll
    for (int i = 0; i < 2; i++)
#pragma unroll
      for (int jt = 0; jt < 4; jt++) qacc[i][jt] = fz;
#pragma unroll
    for (int kc = 0; kc < 2; kc++) {
      bfx8 a0 = ldfrag(&hA[(wv * 32 + mm) * 72 + kc * 32 + qd * 8]);
      bfx8 a1 = ldfrag(&hA[(wv * 32 + 16 + mm) * 72 + kc * 32 + qd * 8]);
#pragma unroll
      for (int jt = 0; jt < 4; jt++) {
        bfx8 bqf = ldfrag(&wWqo[(jt * 16 + mm) * 72 + kc * 32 + qd * 8]);
        qacc[0][jt] = MFMA16(a0, bqf, qacc[0][jt]);
        qacc[1][jt] = MFMA16(a1, bqf, qacc[1][jt]);
      }
    }
#pragma unroll
    for (int lt2 = 0; lt2 < 2; lt2++) {
      float4 mu4 = *(const float4*)&mun[wv * 32 + lt2 * 16 + qd * 4];
      float4 rs4 = *(const float4*)&rsn[wv * 32 + lt2 * 16 + qd * 4];
      float muv[4] = {mu4.x, mu4.y, mu4.z, mu4.w};
      float rsv[4] = {rs4.x, rs4.y, rs4.z, rs4.w};
      int l0 = wv * 32 + lt2 * 16 + qd * 4;
#pragma unroll
      for (int jt = 0; jt < 4; jt++) {
        int j = jt * 16 + mm;
        float Sj = SqTq[j], Tj = SqTq[64 + j];
#pragma unroll
        for (int r = 0; r < 4; r++) {
          float q = rsv[r] * (qacc[lt2][jt][r] - muv[r] * Sj) + Tj;
          q = (q > 0.f) ? (q + 1.f) : __expf(q);
          qaA[(l0 + r) * 72 + j] = f2bf(q);
        }
      }
    }
  }
  __syncthreads();

  // ---- readout in place: thread = (4 l, 1 head), 2 rows per pass (R6 fix) ----
  {
    int lt = tid & 31, hd = tid >> 5;
#pragma unroll
    for (int hp = 0; hp < 2; hp++) {
      int lbase = lt * 4 + hp * 2;
      float qv[2][8];
#pragma unroll
      for (int i = 0; i < 2; i++) {
        uint4 u = *(const uint4*)&qaA[(lbase + i) * 72 + hd * 8];
        qv[i][0] = bflo(u.x); qv[i][1] = bfhi(u.x);
        qv[i][2] = bflo(u.y); qv[i][3] = bfhi(u.y);
        qv[i][4] = bflo(u.z); qv[i][5] = bfhi(u.z);
        qv[i][6] = bflo(u.w); qv[i][7] = bfhi(u.w);
      }
      float att[2][8], nrm[2];
#pragma unroll
      for (int i = 0; i < 2; i++) {
        nrm[i] = 1e-6f;
#pragma unroll
        for (int e = 0; e < 8; e++) att[i][e] = 0.f;
      }
#pragma unroll
      for (int d = 0; d < 8; d++) {
        float zd = kvz[512 + hd * 8 + d];
        float4 kva = *(const float4*)&kvz[hd * 64 + d * 8];
        float4 kvb = *(const float4*)&kvz[hd * 64 + d * 8 + 4];
#pragma unroll
        for (int i = 0; i < 2; i++) {
          float qq = qv[i][d];
          nrm[i] = fmaf(qq, zd, nrm[i]);
          att[i][0] = fmaf(qq, kva.x, att[i][0]);
          att[i][1] = fmaf(qq, kva.y, att[i][1]);
          att[i][2] = fmaf(qq, kva.z, att[i][2]);
          att[i][3] = fmaf(qq, kva.w, att[i][3]);
          att[i][4] = fmaf(qq, kvb.x, att[i][4]);
          att[i][5] = fmaf(qq, kvb.y, att[i][5]);
          att[i][6] = fmaf(qq, kvb.z, att[i][6]);
          att[i][7] = fmaf(qq, kvb.w, att[i][7]);
        }
      }
#pragma unroll
      for (int i = 0; i < 2; i++) {
        float inv = 1.f / nrm[i];
        uint4 o;
        o.x = packbf2(att[i][0] * inv, att[i][1] * inv);
        o.y = packbf2(att[i][2] * inv, att[i][3] * inv);
        o.z = packbf2(att[i][4] * inv, att[i][5] * inv);
        o.w = packbf2(att[i][6] * inv, att[i][7] * inv);
        *(uint4*)&qaA[(lbase + i) * 72 + hd * 8] = o;
      }
    }
  }
  __syncthreads();

  // ---- O-MFMA (B-frags from global); epilogue: + residual (xnR LDS) + bo -> yt tiled ----
  {
    f32x4 yacc[2][4];
#pragma unroll
    for (int i = 0; i < 2; i++)
#pragma unroll
      for (int ft = 0; ft < 4; ft++) yacc[i][ft] = fz;
#pragma unroll
    for (int ec = 0; ec < 2; ec++) {
      bfx8 a0 = ldfrag(&qaA[(wv * 32 + mm) * 72 + ec * 32 + qd * 8]);
      bfx8 a1 = ldfrag(&qaA[(wv * 32 + 16 + mm) * 72 + ec * 32 + qd * 8]);
#pragma unroll
      for (int ft = 0; ft < 4; ft++) {
        bfx8 bof = ldfrag(&wWqo[4608 + (ft * 16 + mm) * 72 + ec * 32 + qd * 8]);
        yacc[0][ft] = MFMA16(a0, bof, yacc[0][ft]);
        yacc[1][ft] = MFMA16(a1, bof, yacc[1][ft]);
      }
    }
#pragma unroll
    for (int lt2 = 0; lt2 < 2; lt2++) {
      int l0 = wv * 32 + lt2 * 16 + qd * 4;
#pragma unroll
      for (int ft = 0; ft < 4; ft++) {
        int ff = ft * 16 + mm;
        float bof = kvz[576 + ff];
        float v0 = yacc[lt2][ft][0] + bf1(xnR[(l0 + 0) * 72 + ff]) + bof;
        float v1 = yacc[lt2][ft][1] + bf1(xnR[(l0 + 1) * 72 + ff]) + bof;
        float v2 = yacc[lt2][ft][2] + bf1(xnR[(l0 + 2) * 72 + ff]) + bof;
        float v3 = yacc[lt2][ft][3] + bf1(xnR[(l0 + 3) * 72 + ff]) + bof;
        uint2 o2;
        o2.x = packbf2(v0, v1);
        o2.y = packbf2(v2, v3);
        // tiled layout [b][l/32][f 64][32]: lgrp = L0/32 + wv, lpos = lt2*16+qd*4
        size_t idx = (((size_t)b * (NL / 32) + (L0 >> 5) + wv) * 64 + ff) * 32 + lt2 * 16 + qd * 4;
        *(uint2*)&ytb[idx] = o2;
      }
    }
  }
}

// ---------------- K4: temporal GEMM via MFMA, tiled layouts, no LDS ----------------
// TSPLIT=16: grid 512 (2 blocks/CU), 16 lg-groups each; atomic contention halved.
__global__ __launch_bounds__(256) void k_temporal(
    const unsigned short* __restrict__ ytb, const unsigned short* __restrict__ wlb,
    float* __restrict__ out2) {
  const int tid = threadIdx.x, lane = tid & 63, wvx = tid >> 6;
  const int mm = lane & 15, qd = lane >> 4;
  const int b = blockIdx.x / TSPLIT;
  const int kc = blockIdx.x % TSPLIT;
  const f32x4 fz = {0.f, 0.f, 0.f, 0.f};
  f32x4 acc[6];
#pragma unroll
  for (int pt = 0; pt < 6; pt++) acc[pt] = fz;

#pragma unroll 2
  for (int ks = 0; ks < NL / 32 / TSPLIT; ks++) {
    int lg = kc * (NL / 32 / TSPLIT) + ks;
    bfx8 bfr = ldfrag(&ytb[(((size_t)b * (NL / 32) + lg) * 64 + wvx * 16 + mm) * 32 + qd * 8]);
#pragma unroll
    for (int pt = 0; pt < 6; pt++) {
      bfx8 afr = ldfrag(&wlb[((size_t)lg * NP + pt * 16 + mm) * 32 + qd * 8]);
      acc[pt] = MFMA16(afr, bfr, acc[pt]);
    }
  }
  const int ff = wvx * 16 + mm;
#pragma unroll
  for (int pt = 0; pt < 6; pt++) {
#pragma unroll
    for (int r = 0; r < 4; r++) {
      int p = pt * 16 + qd * 4 + r;
      atomicAdd(&out2[((size_t)(b * NP + p)) * NF + ff], acc[pt][r]);
    }
  }
}

// ---------------- K5: +blin, RevIN denorm, projector (4 rows per block) ----------------
__global__ __launch_bounds__(256) void k_final(
    const float* __restrict__ out2, const float* __restrict__ blin,
    const float* __restrict__ gamma, const float* __restrict__ beta,
    const float* __restrict__ wmean, const float* __restrict__ wstd,
    const float* __restrict__ Wp, const float* __restrict__ bp0,
    float* __restrict__ out) {
  int bp = blockIdx.x * 4 + (threadIdx.x >> 6);
  int f = threadIdx.x & 63;
  int b = bp / NP, p = bp % NP;
  float v = out2[(size_t)bp * NF + f] + blin[p];
  v = (v - beta[f]) / gamma[f];
  v = v * wstd[b * NF + f] + wmean[b * NF + f];
  float s = v * Wp[f];
#pragma unroll
  for (int off = 32; off > 0; off >>= 1)
    s += __shfl_down(s, off, 64);
  if (f == 0) out[bp] = s + bp0[0];
}

extern "C" void kernel_launch(void* const* d_in, const int* in_sizes, int n_in,
                              void* d_out, int out_size, void* d_ws, size_t ws_size,
                              hipStream_t stream) {
  const float* x     = (const float*)d_in[0];
  const float* gamma = (const float*)d_in[1];
  const float* beta  = (const float*)d_in[2];
  const float* lnw   = (const float*)d_in[3];
  const float* lnb   = (const float*)d_in[4];
  const float* Wq    = (const float*)d_in[5];
  const float* bq    = (const float*)d_in[6];
  const float* Wk    = (const float*)d_in[7];
  const float* bk    = (const float*)d_in[8];
  const float* Wv    = (const float*)d_in[9];
  const float* bv    = (const float*)d_in[10];
  const float* Wo    = (const float*)d_in[11];
  const float* bo    = (const float*)d_in[12];
  const float* Wlin  = (const float*)d_in[13];
  const float* blin  = (const float*)d_in[14];
  const float* Wp    = (const float*)d_in[15];
  const float* bp    = (const float*)d_in[16];
  float* out = (float*)d_out;
  float* ws  = (float*)d_ws;

  float* wmean = ws + WS_MEAN;
  float* wstd  = ws + WS_STD;
  float* wrstd = ws + WS_RSTD;
  float* wKV   = ws + WS_KV;
  float* wZ    = ws + WS_Z;
  float* wout2 = ws + WS_OUT2;
  float* wmun  = ws + WS_MUN;
  float* wrsn  = ws + WS_RSN;
  unsigned short* wlb = (unsigned short*)(ws + WS_WLB);
  unsigned short* ytb = (unsigned short*)(ws + WS_YT);
  unsigned short* wWkv = (unsigned short*)(ws + WS_WKV);
  unsigned short* wWqo = (unsigned short*)(ws + WS_WQO);
  float* wSkT = ws + WS_SKT;
  float* wSqT = ws + WS_SQT;

  // k_pre: stats (2048, also zeroes accum) + wlb (384) + weight-fold (2)
  k_pre<<<NB * NF + NP * NL / 8 / 256 + 2, 256, 0, stream>>>(
      x, Wlin, lnw, lnb, Wk, bk, Wv, bv, Wq, bq, Wo,
      wmean, wstd, wrstd, wlb, wKV, wWkv, wWqo, wSkT, wSqT);
  k_kv<<<NB * 64, 256, 0, stream>>>(x, gamma, beta, wWkv, wSkT,
                                    wmean, wrstd, wKV, wZ, wmun, wrsn);
  k_qy<<<NB * 64, 256, 0, stream>>>(x, gamma, beta, wWqo, wSqT, bo,
                                    wmean, wrstd, wmun, wrsn, wKV, wZ, ytb);
  k_temporal<<<NB * TSPLIT, 256, 0, stream>>>(ytb, wlb, wout2);
  k_final<<<NB * NP / 4, 256, 0, stream>>>(wout2, blin, gamma, beta, wmean, wstd, Wp, bp, out);
}

// Round 11
// 209.741 us; speedup vs baseline: 1.0346x; 1.0346x over previous
//
#include <hip/hip_runtime.h>
#include <cstddef>

#define NB 32
#define NF 64
#define NL 8192
#define NP 96
#define NH 8
#define TSPLIT 16

// ws layout in floats:
#define WS_MEAN 0           // 2048
#define WS_STD  2048        // 2048
#define WS_RSTD 4096        // 2048
#define WS_KV   6144        // NB*NH*64 = 16384
#define WS_Z    22528       // NB*NH*8  = 2048
#define WS_OUT2 24576       // NB*NP*NF = 196608 -> ends 221184
#define WS_MUN  221184      // NB*NL = 262144
#define WS_RSN  483328      // NB*NL = 262144
#define WS_WLB  745472      // NP*NL bf16 = 393216 floats
#define WS_XNB  1138688     // NB*NF*NL bf16 = 8388608 floats
#define WS_YT   9527296     // NB*NF*NL bf16 = 8388608 floats -> ends 17915904
#define WS_WKV  17915904    // prefolded WkB|WvB images: 2*64*72 bf16 = 4608 floats
#define WS_WQO  17920512    // prefolded WqB|WoB images: 4608 floats
#define WS_SKT  17925120    // 256 floats: Sk|Tk+bk|Sv|Tv+bv
#define WS_SQT  17925376    // 128 floats: Sq|Tq+bq   (total ~71.7 MB)

typedef __bf16 bfx8 __attribute__((ext_vector_type(8)));
typedef float f32x4 __attribute__((ext_vector_type(4)));
#define MFMA16(a, b, c) __builtin_amdgcn_mfma_f32_16x16x32_bf16((a), (b), (c), 0, 0, 0)

// ---- bf16 helpers (manual RNE — the ONLY proven spill-free + correct path:
// R3/R4: (__bf16) cast spills to scratch (+20MB WRITE_SIZE); R5: inline-asm
// v_cvt_pk_bf16_f32 produced NaN. Do not change without disasm verification. ----
__device__ __forceinline__ unsigned short f2bf(float f) {
  unsigned u = __float_as_uint(f);
  unsigned r = u + 0x7FFFu + ((u >> 16) & 1u);
  return (unsigned short)(r >> 16);
}
__device__ __forceinline__ unsigned packbf2(float lo, float hi) {
  return (unsigned)f2bf(lo) | ((unsigned)f2bf(hi) << 16);
}
__device__ __forceinline__ float bflo(unsigned d) { return __uint_as_float(d << 16); }
__device__ __forceinline__ float bfhi(unsigned d) { return __uint_as_float(d & 0xFFFF0000u); }
__device__ __forceinline__ float bf1(unsigned short s) { return __uint_as_float(((unsigned)s) << 16); }

__device__ __forceinline__ bfx8 ldfrag(const unsigned short* p) {
  uint4 u = *(const uint4*)p;
  return __builtin_bit_cast(bfx8, u);
}

// ---------------- K_pre: RevIN stats + Wlin tiling + zero accum + weight prefold ----------------
// grid = NB*NF (stats+zero) + 384 (wlb) + 2 (weight fold K/V and Q/O).
__global__ __launch_bounds__(256) void k_pre(
    const float* __restrict__ x, const float* __restrict__ Wlin,
    const float* __restrict__ lnw, const float* __restrict__ lnb,
    const float* __restrict__ Wk, const float* __restrict__ bk,
    const float* __restrict__ Wv, const float* __restrict__ bv,
    const float* __restrict__ Wq, const float* __restrict__ bq,
    const float* __restrict__ Wo,
    float* __restrict__ wmean, float* __restrict__ wstd, float* __restrict__ wrstd,
    unsigned short* __restrict__ wlb, float* __restrict__ zz,
    unsigned short* __restrict__ wWkv, unsigned short* __restrict__ wWqo,
    float* __restrict__ wSkT, float* __restrict__ wSqT) {
  __shared__ float r1[4], r2[4];
  const int bid = blockIdx.x, tid = threadIdx.x;
  if (bid < NB * NF) {
    const float4* row4 = (const float4*)(x + (size_t)bid * NL);
    float s1 = 0.f, s2 = 0.f;
#pragma unroll
    for (int i = 0; i < NL / 4 / 256; i++) {
      float4 v = row4[tid + i * 256];
      s1 += v.x + v.y + v.z + v.w;
      s2 += v.x * v.x + v.y * v.y + v.z * v.z + v.w * v.w;
    }
#pragma unroll
    for (int off = 32; off > 0; off >>= 1) {
      s1 += __shfl_down(s1, off, 64);
      s2 += __shfl_down(s2, off, 64);
    }
    if ((tid & 63) == 0) { r1[tid >> 6] = s1; r2[tid >> 6] = s2; }
    __syncthreads();
    if (tid == 0) {
      s1 = r1[0] + r1[1] + r1[2] + r1[3];
      s2 = r2[0] + r2[1] + r2[2] + r2[3];
      float m = s1 * (1.f / NL);
      float var = (s2 - (float)NL * m * m) * (1.f / (NL - 1));
      float sd = sqrtf(fmaxf(var, 0.f)) + 1e-5f;
      wmean[bid] = m;
      wstd[bid] = sd;
      wrstd[bid] = 1.f / sd;
    }
    // zero the atomic accumulators (wKV 16384 + wZ 2048 + out2 196608 = 215040 floats)
    unsigned zi = (unsigned)bid * 256u + (unsigned)tid;
    if (zi < 215040u) zz[zi] = 0.f;
  } else if (bid < NB * NF + NP * NL / 8 / 256) {
    int i = (bid - NB * NF) * 256 + tid;  // NP*NL/8 threads
    int p = i >> 10;                      // NL/8 = 1024
    int l8 = (i & 1023) * 8;
    float4 va = *(const float4*)&Wlin[(size_t)p * NL + l8];
    float4 vb = *(const float4*)&Wlin[(size_t)p * NL + l8 + 4];
    uint4 o;
    o.x = packbf2(va.x, va.y); o.y = packbf2(va.z, va.w);
    o.z = packbf2(vb.x, vb.y); o.w = packbf2(vb.z, vb.w);
    *(uint4*)&wlb[(((size_t)(l8 >> 5)) * NP + p) * 32 + (l8 & 31)] = o;
  } else if (bid == NB * NF + NP * NL / 8 / 256) {
    // ---- fold K/V weights (lnw) + S/T(+bias) into global images ----
    int jj = tid >> 2, g = tid & 3;
    int f0 = g * 16;
    float tkp = 0.f, tvp = 0.f, skp = 0.f, svp = 0.f;
#pragma unroll
    for (int i = 0; i < 4; i++) {
      int f = f0 + i * 4;
      float4 wk4 = *(const float4*)&Wk[jj * NF + f];
      float4 wv4 = *(const float4*)&Wv[jj * NF + f];
      float4 lw  = *(const float4*)&lnw[f];
      float4 lb  = *(const float4*)&lnb[f];
      uint2 pk2, pv2;
      pk2.x = packbf2(wk4.x * lw.x, wk4.y * lw.y);
      pk2.y = packbf2(wk4.z * lw.z, wk4.w * lw.w);
      pv2.x = packbf2(wv4.x * lw.x, wv4.y * lw.y);
      pv2.y = packbf2(wv4.z * lw.z, wv4.w * lw.w);
      *(uint2*)&wWkv[jj * 72 + f] = pk2;
      *(uint2*)&wWkv[4608 + jj * 72 + f] = pv2;
      tkp += lb.x * wk4.x + lb.y * wk4.y + lb.z * wk4.z + lb.w * wk4.w;
      tvp += lb.x * wv4.x + lb.y * wv4.y + lb.z * wv4.z + lb.w * wv4.w;
      skp += bflo(pk2.x) + bfhi(pk2.x) + bflo(pk2.y) + bfhi(pk2.y);
      svp += bflo(pv2.x) + bfhi(pv2.x) + bflo(pv2.y) + bfhi(pv2.y);
    }
    tkp += __shfl_xor(tkp, 1, 64); tkp += __shfl_xor(tkp, 2, 64);
    tvp += __shfl_xor(tvp, 1, 64); tvp += __shfl_xor(tvp, 2, 64);
    skp += __shfl_xor(skp, 1, 64); skp += __shfl_xor(skp, 2, 64);
    svp += __shfl_xor(svp, 1, 64); svp += __shfl_xor(svp, 2, 64);
    if (g == 0) {
      wSkT[jj]       = skp;
      wSkT[64 + jj]  = tkp + bk[jj];
      wSkT[128 + jj] = svp;
      wSkT[192 + jj] = tvp + bv[jj];
    }
  } else {
    // ---- fold Q (lnw) + raw Wo + Sq/Tq(+bq) ----
    int jj = tid >> 2, g = tid & 3;
    int f0 = g * 16;
    float tqp = 0.f, sqp = 0.f;
#pragma unroll
    for (int i = 0; i < 4; i++) {
      int f = f0 + i * 4;
      float4 wq4 = *(const float4*)&Wq[jj * NF + f];
      float4 wo4 = *(const float4*)&Wo[jj * NF + f];
      float4 lw  = *(const float4*)&lnw[f];
      float4 lb  = *(const float4*)&lnb[f];
      uint2 pq2, po2;
      pq2.x = packbf2(wq4.x * lw.x, wq4.y * lw.y);
      pq2.y = packbf2(wq4.z * lw.z, wq4.w * lw.w);
      po2.x = packbf2(wo4.x, wo4.y);
      po2.y = packbf2(wo4.z, wo4.w);
      *(uint2*)&wWqo[jj * 72 + f] = pq2;
      *(uint2*)&wWqo[4608 + jj * 72 + f] = po2;
      tqp += lb.x * wq4.x + lb.y * wq4.y + lb.z * wq4.z + lb.w * wq4.w;
      sqp += bflo(pq2.x) + bfhi(pq2.x) + bflo(pq2.y) + bfhi(pq2.y);
    }
    tqp += __shfl_xor(tqp, 1, 64); tqp += __shfl_xor(tqp, 2, 64);
    sqp += __shfl_xor(sqp, 1, 64); sqp += __shfl_xor(sqp, 2, 64);
    if (g == 0) { wSqT[jj] = sqp; wSqT[64 + jj] = tqp + bq[jj]; }
  }
}

// ---------------- K2: K/V projection (MFMA) + KV,Z accumulation + xn export ----------------
// 256 threads, 128 l per block, grid NB*64.  LDS 20992 B.  (R9's best-measured k_kv: 41.2 µs)
// Weights as MFMA frags from global prefolded images (L2-hot); KV-reduction in two l-halves.
__global__ __launch_bounds__(256, 4) void k_kv(
    const float* __restrict__ x,
    const float* __restrict__ gamma, const float* __restrict__ beta,
    const unsigned short* __restrict__ wWkv, const float* __restrict__ wSkT,
    const float* __restrict__ wmean, const float* __restrict__ wrstd,
    float* __restrict__ wKV, float* __restrict__ wZ,
    float* __restrict__ wmun, float* __restrict__ wrsn,
    unsigned short* __restrict__ xnb) {
  __shared__ __align__(16) char smem[20992];
  unsigned short* hA  = (unsigned short*)smem;            // [128][72] xn bf16
  unsigned short* pKh = (unsigned short*)smem;            // overlay: [64 j][72] l-half
  unsigned short* pVh = (unsigned short*)(smem + 9216);   // overlay: [64 j][72] l-half
  float* SkT = (float*)(smem + 18432);  // [256] Sk|Tk|Sv|Tv
  float* mun = (float*)(smem + 19456);  // [128]
  float* rsn = (float*)(smem + 19968);  // [128]
  float* cbc = (float*)(smem + 20480);  // [128]  (cb,cc) pairs per f

  const int tid = threadIdx.x;
  const int b = blockIdx.x >> 6;
  const int tI = blockIdx.x & 63;
  const int L0 = tI * 128;
  const int lane = tid & 63, wv = tid >> 6;
  const int mm = lane & 15, qd = lane >> 4;

  // ---- phase 0: RevIN fold constants + SkT copy ----
  if (tid < 64) {
    float cb = wrstd[b * NF + tid] * gamma[tid];
    cbc[2 * tid] = cb;
    cbc[2 * tid + 1] = beta[tid] - wmean[b * NF + tid] * cb;
  }
  SkT[tid] = wSkT[tid];
  __syncthreads();

  // ---- phase 1: thread = (l-quad lt, f-octet fg); 8x dwordx4 loads ----
  {
    const int lt = tid >> 3;       // 0..31
    const int fg = tid & 7;        // 0..7
    const int l0q = lt * 4;
    const float* xp = x + ((size_t)(b * NF + fg * 8)) * NL + L0 + l0q;
    f32x4 v[8];
#pragma unroll
    for (int i = 0; i < 8; i++) v[i] = *(const f32x4*)(xp + (size_t)i * NL);
    float a[8][4];
#pragma unroll
    for (int i = 0; i < 4; i++) {
      float4 c = *(const float4*)&cbc[fg * 16 + i * 4];  // cb,cc for f=fg*8+2i, +2i+1
#pragma unroll
      for (int j = 0; j < 4; j++) {
        a[2 * i][j]     = fmaf(v[2 * i][j], c.x, c.y);
        a[2 * i + 1][j] = fmaf(v[2 * i + 1][j], c.z, c.w);
      }
    }
    float s1[4], s2[4];
#pragma unroll
    for (int j = 0; j < 4; j++) {
      s1[j] = 0.f; s2[j] = 0.f;
#pragma unroll
      for (int i = 0; i < 8; i++) {
        s1[j] += a[i][j];
        s2[j] = fmaf(a[i][j], a[i][j], s2[j]);
      }
    }
    // reduce over fg (lane bits 0..2)
#pragma unroll
    for (int m = 1; m <= 4; m <<= 1) {
#pragma unroll
      for (int j = 0; j < 4; j++) {
        s1[j] += __shfl_xor(s1[j], m, 64);
        s2[j] += __shfl_xor(s2[j], m, 64);
      }
    }
    // pack + store (LDS + global) straight from regs
#pragma unroll
    for (int j = 0; j < 4; j++) {
      uint4 o;
      o.x = packbf2(a[0][j], a[1][j]);
      o.y = packbf2(a[2][j], a[3][j]);
      o.z = packbf2(a[4][j], a[5][j]);
      o.w = packbf2(a[6][j], a[7][j]);
      *(uint4*)&hA[(l0q + j) * 72 + fg * 8] = o;
      *(uint4*)(xnb + (((size_t)(b * 64 + tI) * 128 + l0q + j) * 64 + fg * 8)) = o;
    }
    if (fg == 0) {
      float mv[4], rv[4];
#pragma unroll
      for (int j = 0; j < 4; j++) {
        float mu = s1[j] * (1.f / NF);
        float var = s2[j] * (1.f / NF) - mu * mu;
        mv[j] = mu;
        rv[j] = rsqrtf(fmaxf(var, 0.f) + 1e-5f);
      }
      float4 m4 = {mv[0], mv[1], mv[2], mv[3]};
      float4 r4 = {rv[0], rv[1], rv[2], rv[3]};
      *(float4*)&mun[l0q] = m4;
      *(float4*)&rsn[l0q] = r4;
      *(float4*)&wmun[(size_t)b * NL + L0 + l0q] = m4;
      *(float4*)&wrsn[(size_t)b * NL + L0 + l0q] = r4;
    }
  }
  __syncthreads();

  // ---- projection MFMA: A-frags from LDS hA, B-frags from global wWkv (L2-hot) ----
  const f32x4 fz = {0.f, 0.f, 0.f, 0.f};
  f32x4 kacc[2][4], vacc[2][4];
#pragma unroll
  for (int i = 0; i < 2; i++)
#pragma unroll
    for (int jt = 0; jt < 4; jt++) { kacc[i][jt] = fz; vacc[i][jt] = fz; }

#pragma unroll
  for (int kc = 0; kc < 2; kc++) {
    bfx8 a0 = ldfrag(&hA[(wv * 32 + mm) * 72 + kc * 32 + qd * 8]);
    bfx8 a1 = ldfrag(&hA[(wv * 32 + 16 + mm) * 72 + kc * 32 + qd * 8]);
#pragma unroll
    for (int jt = 0; jt < 4; jt++) {
      bfx8 bkf = ldfrag(&wWkv[(jt * 16 + mm) * 72 + kc * 32 + qd * 8]);
      bfx8 bvf = ldfrag(&wWkv[4608 + (jt * 16 + mm) * 72 + kc * 32 + qd * 8]);
      kacc[0][jt] = MFMA16(a0, bkf, kacc[0][jt]);
      kacc[1][jt] = MFMA16(a1, bkf, kacc[1][jt]);
      vacc[0][jt] = MFMA16(a0, bvf, vacc[0][jt]);
      vacc[1][jt] = MFMA16(a1, bvf, vacc[1][jt]);
    }
  }

  // ---- postfix: K = rs*(raw - mu*Sk) + Tk -> phi;  V likewise (no phi) ----
#pragma unroll
  for (int lt2 = 0; lt2 < 2; lt2++) {
    float4 mu4 = *(const float4*)&mun[wv * 32 + lt2 * 16 + qd * 4];
    float4 rs4 = *(const float4*)&rsn[wv * 32 + lt2 * 16 + qd * 4];
    float muv[4] = {mu4.x, mu4.y, mu4.z, mu4.w};
    float rsv[4] = {rs4.x, rs4.y, rs4.z, rs4.w};
#pragma unroll
    for (int jt = 0; jt < 4; jt++) {
      int j = jt * 16 + mm;
      float Sk = SkT[j], Tk = SkT[64 + j], Sv = SkT[128 + j], Tv = SkT[192 + j];
#pragma unroll
      for (int r = 0; r < 4; r++) {
        float kk = rsv[r] * (kacc[lt2][jt][r] - muv[r] * Sk) + Tk;
        kacc[lt2][jt][r] = (kk > 0.f) ? (kk + 1.f) : __expf(kk);
        vacc[lt2][jt][r] = rsv[r] * (vacc[lt2][jt][r] - muv[r] * Sv) + Tv;
      }
    }
  }

  // ---- Z from f32 kacc regs: wave wv covers l = wv*32..+32 ----
  {
#pragma unroll
    for (int jt = 0; jt < 4; jt++) {
      float z = 0.f;
#pragma unroll
      for (int lt2 = 0; lt2 < 2; lt2++)
#pragma unroll
        for (int r = 0; r < 4; r++) z += kacc[lt2][jt][r];
      z += __shfl_xor(z, 16, 64);
      z += __shfl_xor(z, 32, 64);
      if (qd == 0) atomicAdd(&wZ[b * 64 + jt * 16 + mm], z);
    }
  }

  // ---- KV reduction in two l-halves through the overlay (hA dead) ----
  {
    f32x4 racc = fz;
#pragma unroll
    for (int h = 0; h < 2; h++) {
      __syncthreads();   // prior reads of overlay (or hA) complete
      if ((wv >> 1) == h) {
#pragma unroll
        for (int lt2 = 0; lt2 < 2; lt2++) {
          int lcol = (wv & 1) * 32 + lt2 * 16 + qd * 4;
#pragma unroll
          for (int jt = 0; jt < 4; jt++) {
            int j = jt * 16 + mm;
            uint2 dk, dv;
            dk.x = packbf2(kacc[lt2][jt][0], kacc[lt2][jt][1]);
            dk.y = packbf2(kacc[lt2][jt][2], kacc[lt2][jt][3]);
            dv.x = packbf2(vacc[lt2][jt][0], vacc[lt2][jt][1]);
            dv.y = packbf2(vacc[lt2][jt][2], vacc[lt2][jt][3]);
            *(uint2*)&pKh[j * 72 + lcol] = dk;
            *(uint2*)&pVh[j * 72 + lcol] = dv;
          }
        }
      }
      __syncthreads();
#pragma unroll
      for (int kb = 0; kb < 2; kb++) {
        bfx8 ak  = ldfrag(&pKh[(wv * 16 + mm) * 72 + kb * 32 + qd * 8]);
        bfx8 bv8 = ldfrag(&pVh[(wv * 16 + mm) * 72 + kb * 32 + qd * 8]);
        racc = MFMA16(ak, bv8, racc);
      }
    }
    int eh = mm >> 3, e = mm & 7;
#pragma unroll
    for (int r = 0; r < 4; r++) {
      int row = qd * 4 + r;
      if ((row >> 3) == eh)
        atomicAdd(&wKV[(b * NH + wv * 2 + eh) * 64 + (row & 7) * 8 + e], racc[r]);
    }
  }
}

// ---------------- K3: Q MFMA + readout + O MFMA + residual -> yT tiled bf16 ----------------
// 256 threads, 128 l, grid NB*64.  LDS 40960 B -> 4 blocks/CU.  (R8's best-measured k_qy)
// Weights copied from prefolded global image into LDS; readout in 2-row passes (R6 fix).
__global__ __launch_bounds__(256, 4) void k_qy(
    const unsigned short* __restrict__ xnb,
    const unsigned short* __restrict__ wWqo, const float* __restrict__ wSqT,
    const float* __restrict__ bo,
    const float* __restrict__ wmun, const float* __restrict__ wrsn,
    const float* __restrict__ wKV, const float* __restrict__ wZ,
    unsigned short* __restrict__ ytb) {
  __shared__ __align__(16) char smem[40960];
  unsigned short* hA  = (unsigned short*)smem;             // [128][72] xn bf16 -> overlaid by att
  unsigned short* qaA = (unsigned short*)smem;             // [128 l][72] phi(Q)/att
  unsigned short* WqB = (unsigned short*)(smem + 18432);   // [64 j][72 f] folded (WqB|WoB contiguous)
  unsigned short* WoB = (unsigned short*)(smem + 27648);   // [64 f][72 e]
  float* kvz   = (float*)(smem + 36864);  // [640] KV|Z|bo
  float* mun   = (float*)(smem + 39424);  // [128]
  float* rsn   = (float*)(smem + 39936);  // [128]
  float* SqTq  = (float*)(smem + 40448);  // [128]

  const int tid = threadIdx.x;
  const int b = blockIdx.x >> 6;
  const int tI = blockIdx.x & 63;
  const int L0 = tI * 128;
  const int lane = tid & 63, wv = tid >> 6;
  const int mm = lane & 15, qd = lane >> 4;
  const unsigned short* xtile = xnb + (size_t)(b * 64 + tI) * 128 * 64;

  // ---- phase 0: copy prefolded weights + SqT + kvz/bo + xn tile + mu/rs ----
  {
    uint4* dst = (uint4*)(smem + 18432);
    const uint4* src = (const uint4*)wWqo;
#pragma unroll
    for (int i = 0; i < 4; i++) dst[tid + i * 256] = src[tid + i * 256];
    if (tid < 128) dst[tid + 1024] = src[tid + 1024];   // 1152 uint4 total
    if (tid < 128) SqTq[tid] = wSqT[tid];
  }
  for (int i = tid; i < 640; i += 256)
    kvz[i] = (i < 512) ? wKV[b * 512 + i] : (i < 576 ? wZ[b * 64 + i - 512] : bo[i - 576]);
  {
    int row = tid >> 1, half = tid & 1;
    const uint4* s4 = (const uint4*)(xtile + (size_t)row * 64 + half * 32);
    uint4 u0 = s4[0], u1 = s4[1], u2 = s4[2], u3 = s4[3];
    uint4* d4 = (uint4*)&hA[row * 72 + half * 32];
    d4[0] = u0; d4[1] = u1; d4[2] = u2; d4[3] = u3;
  }
  if (tid < 64) {
    int h = tid >> 5, i = tid & 31;
    const float* src = h ? wrsn : wmun;
    float4 v = *(const float4*)&src[(size_t)b * NL + L0 + i * 4];
    *(float4*)&((h ? rsn : mun)[i * 4]) = v;
  }
  __syncthreads();

  const f32x4 fz = {0.f, 0.f, 0.f, 0.f};

  // ---- Q-MFMA; postfix+phi scatters into qaA (overlay of hA, own l-rows only) ----
  {
    f32x4 qacc[2][4];
#pragma unroll
    for (int i = 0; i < 2; i++)
#pragma unroll
      for (int jt = 0; jt < 4; jt++) qacc[i][jt] = fz;
#pragma unroll
    for (int kc = 0; kc < 2; kc++) {
      bfx8 a0 = ldfrag(&hA[(wv * 32 + mm) * 72 + kc * 32 + qd * 8]);
      bfx8 a1 = ldfrag(&hA[(wv * 32 + 16 + mm) * 72 + kc * 32 + qd * 8]);
#pragma unroll
      for (int jt = 0; jt < 4; jt++) {
        bfx8 bqf = ldfrag(&WqB[(jt * 16 + mm) * 72 + kc * 32 + qd * 8]);
        qacc[0][jt] = MFMA16(a0, bqf, qacc[0][jt]);
        qacc[1][jt] = MFMA16(a1, bqf, qacc[1][jt]);
      }
    }
#pragma unroll
    for (int lt2 = 0; lt2 < 2; lt2++) {
      float4 mu4 = *(const float4*)&mun[wv * 32 + lt2 * 16 + qd * 4];
      float4 rs4 = *(const float4*)&rsn[wv * 32 + lt2 * 16 + qd * 4];
      float muv[4] = {mu4.x, mu4.y, mu4.z, mu4.w};
      float rsv[4] = {rs4.x, rs4.y, rs4.z, rs4.w};
      int l0 = wv * 32 + lt2 * 16 + qd * 4;
#pragma unroll
      for (int jt = 0; jt < 4; jt++) {
        int j = jt * 16 + mm;
        float Sj = SqTq[j], Tj = SqTq[64 + j];
#pragma unroll
        for (int r = 0; r < 4; r++) {
          float q = rsv[r] * (qacc[lt2][jt][r] - muv[r] * Sj) + Tj;
          q = (q > 0.f) ? (q + 1.f) : __expf(q);
          qaA[(l0 + r) * 72 + j] = f2bf(q);
        }
      }
    }
  }
  __syncthreads();

  // ---- readout in place: thread = (4 l, 1 head), 2 rows per pass (R6 fix) ----
  {
    int lt = tid & 31, hd = tid >> 5;
#pragma unroll
    for (int hp = 0; hp < 2; hp++) {
      int lbase = lt * 4 + hp * 2;
      float qv[2][8];
#pragma unroll
      for (int i = 0; i < 2; i++) {
        uint4 u = *(const uint4*)&qaA[(lbase + i) * 72 + hd * 8];
        qv[i][0] = bflo(u.x); qv[i][1] = bfhi(u.x);
        qv[i][2] = bflo(u.y); qv[i][3] = bfhi(u.y);
        qv[i][4] = bflo(u.z); qv[i][5] = bfhi(u.z);
        qv[i][6] = bflo(u.w); qv[i][7] = bfhi(u.w);
      }
      float att[2][8], nrm[2];
#pragma unroll
      for (int i = 0; i < 2; i++) {
        nrm[i] = 1e-6f;
#pragma unroll
        for (int e = 0; e < 8; e++) att[i][e] = 0.f;
      }
#pragma unroll
      for (int d = 0; d < 8; d++) {
        float zd = kvz[512 + hd * 8 + d];
        float4 kva = *(const float4*)&kvz[hd * 64 + d * 8];
        float4 kvb = *(const float4*)&kvz[hd * 64 + d * 8 + 4];
#pragma unroll
        for (int i = 0; i < 2; i++) {
          float qq = qv[i][d];
          nrm[i] = fmaf(qq, zd, nrm[i]);
          att[i][0] = fmaf(qq, kva.x, att[i][0]);
          att[i][1] = fmaf(qq, kva.y, att[i][1]);
          att[i][2] = fmaf(qq, kva.z, att[i][2]);
          att[i][3] = fmaf(qq, kva.w, att[i][3]);
          att[i][4] = fmaf(qq, kvb.x, att[i][4]);
          att[i][5] = fmaf(qq, kvb.y, att[i][5]);
          att[i][6] = fmaf(qq, kvb.z, att[i][6]);
          att[i][7] = fmaf(qq, kvb.w, att[i][7]);
        }
      }
#pragma unroll
      for (int i = 0; i < 2; i++) {
        float inv = 1.f / nrm[i];
        uint4 o;
        o.x = packbf2(att[i][0] * inv, att[i][1] * inv);
        o.y = packbf2(att[i][2] * inv, att[i][3] * inv);
        o.z = packbf2(att[i][4] * inv, att[i][5] * inv);
        o.w = packbf2(att[i][6] * inv, att[i][7] * inv);
        *(uint4*)&qaA[(lbase + i) * 72 + hd * 8] = o;
      }
    }
  }
  __syncthreads();

  // ---- O-MFMA; epilogue: + residual (global xnb, L2/L3-hot) + bo -> yt tiled ----
  {
    f32x4 yacc[2][4];
#pragma unroll
    for (int i = 0; i < 2; i++)
#pragma unroll
      for (int ft = 0; ft < 4; ft++) yacc[i][ft] = fz;
#pragma unroll
    for (int ec = 0; ec < 2; ec++) {
      bfx8 a0 = ldfrag(&qaA[(wv * 32 + mm) * 72 + ec * 32 + qd * 8]);
      bfx8 a1 = ldfrag(&qaA[(wv * 32 + 16 + mm) * 72 + ec * 32 + qd * 8]);
#pragma unroll
      for (int ft = 0; ft < 4; ft++) {
        bfx8 bof = ldfrag(&WoB[(ft * 16 + mm) * 72 + ec * 32 + qd * 8]);
        yacc[0][ft] = MFMA16(a0, bof, yacc[0][ft]);
        yacc[1][ft] = MFMA16(a1, bof, yacc[1][ft]);
      }
    }
#pragma unroll
    for (int lt2 = 0; lt2 < 2; lt2++) {
      int l0 = wv * 32 + lt2 * 16 + qd * 4;
#pragma unroll
      for (int ft = 0; ft < 4; ft++) {
        int ff = ft * 16 + mm;
        float bof = kvz[576 + ff];
        float v0 = yacc[lt2][ft][0] + bf1(xtile[(size_t)(l0 + 0) * 64 + ff]) + bof;
        float v1 = yacc[lt2][ft][1] + bf1(xtile[(size_t)(l0 + 1) * 64 + ff]) + bof;
        float v2 = yacc[lt2][ft][2] + bf1(xtile[(size_t)(l0 + 2) * 64 + ff]) + bof;
        float v3 = yacc[lt2][ft][3] + bf1(xtile[(size_t)(l0 + 3) * 64 + ff]) + bof;
        uint2 o2;
        o2.x = packbf2(v0, v1);
        o2.y = packbf2(v2, v3);
        // tiled layout [b][l/32][f 64][32]: lgrp = L0/32 + wv, lpos = lt2*16+qd*4
        size_t idx = (((size_t)b * (NL / 32) + (L0 >> 5) + wv) * 64 + ff) * 32 + lt2 * 16 + qd * 4;
        *(uint2*)&ytb[idx] = o2;
      }
    }
  }
}

// ---------------- K4: temporal GEMM via MFMA, tiled layouts, no LDS ----------------
// TSPLIT=16: grid 512 (2 blocks/CU), 16 lg-groups each; atomic contention halved.
__global__ __launch_bounds__(256) void k_temporal(
    const unsigned short* __restrict__ ytb, const unsigned short* __restrict__ wlb,
    float* __restrict__ out2) {
  const int tid = threadIdx.x, lane = tid & 63, wvx = tid >> 6;
  const int mm = lane & 15, qd = lane >> 4;
  const int b = blockIdx.x / TSPLIT;
  const int kc = blockIdx.x % TSPLIT;
  const f32x4 fz = {0.f, 0.f, 0.f, 0.f};
  f32x4 acc[6];
#pragma unroll
  for (int pt = 0; pt < 6; pt++) acc[pt] = fz;

#pragma unroll 2
  for (int ks = 0; ks < NL / 32 / TSPLIT; ks++) {
    int lg = kc * (NL / 32 / TSPLIT) + ks;
    bfx8 bfr = ldfrag(&ytb[(((size_t)b * (NL / 32) + lg) * 64 + wvx * 16 + mm) * 32 + qd * 8]);
#pragma unroll
    for (int pt = 0; pt < 6; pt++) {
      bfx8 afr = ldfrag(&wlb[((size_t)lg * NP + pt * 16 + mm) * 32 + qd * 8]);
      acc[pt] = MFMA16(afr, bfr, acc[pt]);
    }
  }
  const int ff = wvx * 16 + mm;
#pragma unroll
  for (int pt = 0; pt < 6; pt++) {
#pragma unroll
    for (int r = 0; r < 4; r++) {
      int p = pt * 16 + qd * 4 + r;
      atomicAdd(&out2[((size_t)(b * NP + p)) * NF + ff], acc[pt][r]);
    }
  }
}

// ---------------- K5: +blin, RevIN denorm, projector (4 rows per block) ----------------
__global__ __launch_bounds__(256) void k_final(
    const float* __restrict__ out2, const float* __restrict__ blin,
    const float* __restrict__ gamma, const float* __restrict__ beta,
    const float* __restrict__ wmean, const float* __restrict__ wstd,
    const float* __restrict__ Wp, const float* __restrict__ bp0,
    float* __restrict__ out) {
  int bp = blockIdx.x * 4 + (threadIdx.x >> 6);
  int f = threadIdx.x & 63;
  int b = bp / NP, p = bp % NP;
  float v = out2[(size_t)bp * NF + f] + blin[p];
  v = (v - beta[f]) / gamma[f];
  v = v * wstd[b * NF + f] + wmean[b * NF + f];
  float s = v * Wp[f];
#pragma unroll
  for (int off = 32; off > 0; off >>= 1)
    s += __shfl_down(s, off, 64);
  if (f == 0) out[bp] = s + bp0[0];
}

extern "C" void kernel_launch(void* const* d_in, const int* in_sizes, int n_in,
                              void* d_out, int out_size, void* d_ws, size_t ws_size,
                              hipStream_t stream) {
  const float* x     = (const float*)d_in[0];
  const float* gamma = (const float*)d_in[1];
  const float* beta  = (const float*)d_in[2];
  const float* lnw   = (const float*)d_in[3];
  const float* lnb   = (const float*)d_in[4];
  const float* Wq    = (const float*)d_in[5];
  const float* bq    = (const float*)d_in[6];
  const float* Wk    = (const float*)d_in[7];
  const float* bk    = (const float*)d_in[8];
  const float* Wv    = (const float*)d_in[9];
  const float* bv    = (const float*)d_in[10];
  const float* Wo    = (const float*)d_in[11];
  const float* bo    = (const float*)d_in[12];
  const float* Wlin  = (const float*)d_in[13];
  const float* blin  = (const float*)d_in[14];
  const float* Wp    = (const float*)d_in[15];
  const float* bp    = (const float*)d_in[16];
  float* out = (float*)d_out;
  float* ws  = (float*)d_ws;

  float* wmean = ws + WS_MEAN;
  float* wstd  = ws + WS_STD;
  float* wrstd = ws + WS_RSTD;
  float* wKV   = ws + WS_KV;
  float* wZ    = ws + WS_Z;
  float* wout2 = ws + WS_OUT2;
  float* wmun  = ws + WS_MUN;
  float* wrsn  = ws + WS_RSN;
  unsigned short* wlb = (unsigned short*)(ws + WS_WLB);
  unsigned short* xnb = (unsigned short*)(ws + WS_XNB);
  unsigned short* ytb = (unsigned short*)(ws + WS_YT);
  unsigned short* wWkv = (unsigned short*)(ws + WS_WKV);
  unsigned short* wWqo = (unsigned short*)(ws + WS_WQO);
  float* wSkT = ws + WS_SKT;
  float* wSqT = ws + WS_SQT;

  // k_pre: stats (2048, also zeroes accum) + wlb (384) + weight-fold (2)
  k_pre<<<NB * NF + NP * NL / 8 / 256 + 2, 256, 0, stream>>>(
      x, Wlin, lnw, lnb, Wk, bk, Wv, bv, Wq, bq, Wo,
      wmean, wstd, wrstd, wlb, wKV, wWkv, wWqo, wSkT, wSqT);
  k_kv<<<NB * 64, 256, 0, stream>>>(x, gamma, beta, wWkv, wSkT,
                                    wmean, wrstd, wKV, wZ, wmun, wrsn, xnb);
  k_qy<<<NB * 64, 256, 0, stream>>>(xnb, wWqo, wSqT, bo,
                                    wmun, wrsn, wKV, wZ, ytb);
  k_temporal<<<NB * TSPLIT, 256, 0, stream>>>(ytb, wlb, wout2);
  k_final<<<NB * NP / 4, 256, 0, stream>>>(wout2, blin, gamma, beta, wmean, wstd, Wp, bp, out);
}